// Round 21
// baseline (326.945 us; speedup 1.0000x reference)
//
#include <hip/hip_runtime.h>
#include <hip/hip_bf16.h>
#include <stdint.h>

// ConvMoE: B=32, C=384, H=W=28, E=4, HID=384, K=2. N tokens = 25088.
// r21 = r20 + split-K=2 for GEMM2 (latency-bound wall = one block's chain;
// halving K-steps halves the wall; 1176 blocks still fit co-resident).
// GEMM1: r12's 128x128/BK=32/4-wave/3-buf kernel (53.1us proven).
// GEMM2: r19/r20's 2-wave direct-B kernel, split into K-halves:
//   half0 -> out (+bias/coef terms), half1 -> fp32 partial; reduce adds.
// Runtime ws_size guard: falls back to full-K (r20 exact) if ws too small.
#define B_DIM 32
#define C_DIM 384
#define HW_DIM 784
#define E_DIM 4
#define HID_DIM 384
#define NTOK (B_DIM * HW_DIM)   // 25088
#define NH (E_DIM * HID_DIM)    // 1536
#define WSZ 589824              // NH*C_DIM

using short8 = __attribute__((ext_vector_type(8))) short;
using f32x4  = __attribute__((ext_vector_type(4))) float;
typedef unsigned short ushort_t;

__device__ __forceinline__ ushort_t f2bf(float f) {
  __hip_bfloat16 h = __float2bfloat16(f);
  return __builtin_bit_cast(ushort_t, h);
}

__device__ __forceinline__ void gload_lds16(const void* g, void* l) {
  __builtin_amdgcn_global_load_lds(
      (const __attribute__((address_space(1))) unsigned int*)g,
      (__attribute__((address_space(3))) unsigned int*)l, 16, 0, 0);
}

// ---- kernel 1: W1 linear bf16 + W2 fragment-packed (+ present=0) ------------
__global__ __launch_bounds__(256) void prep_kernel(
    const float* __restrict__ w1, const float* __restrict__ w2,
    ushort_t* __restrict__ W1b, ushort_t* __restrict__ W2f,
    unsigned int* __restrict__ present) {
  int i = blockIdx.x * 256 + threadIdx.x;
  if (i == 0) *present = 0u;
  if (i >= WSZ) return;
  W1b[i] = f2bf(w1[i]);                             // [e*HID+d][c] linear
  {
    // W2f: nt(3) ks(48) chunks of [wn(2)][ni(4)][lane(64)][t(8)]
    int r = i;
    const int nt = r / 196608; r -= nt * 196608;
    const int ks = r / 4096;   r -= ks * 4096;
    const int wn = r >> 11;
    const int ni = (r >> 9) & 3;
    const int ln = (r >> 3) & 63;
    const int tt = r & 7;
    const int o = nt * 128 + wn * 64 + ni * 16 + (ln & 15);
    const int kg = ks * 32 + (ln >> 4) * 8 + tt;
    const int e = kg / HID_DIM, d = kg - e * HID_DIM;
    W2f[i] = f2bf(w2[((size_t)e * C_DIM + o) * HID_DIM + d]);  // w2 [E][C][HID]
  }
}

// ------- kernel 2: gate + softmax + top2 + x -> bf16 [N][C] (512 thr) --------
__global__ __launch_bounds__(512) void gate_kernel(
    const float* __restrict__ x, const float* __restrict__ gw,
    const float* __restrict__ gb, ushort_t* __restrict__ xb,
    float* __restrict__ topw, unsigned int* __restrict__ present) {
  __shared__ __align__(16) ushort_t lxs[64][392];
  __shared__ float pscore[8][64][4];
  __shared__ unsigned int pmask;
  const int b = blockIdx.x;
  const int p0 = blockIdx.y * 64;
  const int cnt = min(64, HW_DIM - p0);
  const int tid = threadIdx.x;
  const int cg = tid >> 6, tl = tid & 63;
  if (tid == 0) pmask = 0u;
  float a0 = 0.f, a1 = 0.f, a2 = 0.f, a3 = 0.f;
  const bool valid = tl < cnt;
  if (valid) {
    const float* xp = x + (size_t)b * C_DIM * HW_DIM + p0 + tl;
    for (int c = cg; c < C_DIM; c += 8) {
      const float v = xp[(size_t)c * HW_DIM];
      lxs[tl][c] = f2bf(v);
      const float4 g = *(const float4*)&gw[c * 4];
      a0 += v * g.x; a1 += v * g.y; a2 += v * g.z; a3 += v * g.w;
    }
  }
  pscore[cg][tl][0] = a0; pscore[cg][tl][1] = a1;
  pscore[cg][tl][2] = a2; pscore[cg][tl][3] = a3;
  __syncthreads();
  if (cg == 0 && valid) {
    float z[4];
#pragma unroll
    for (int e = 0; e < 4; e++) {
      float s = gb[e];
#pragma unroll
      for (int g8 = 0; g8 < 8; g8++) s += pscore[g8][tl][e];
      z[e] = s;
    }
    const float mx = fmaxf(fmaxf(z[0], z[1]), fmaxf(z[2], z[3]));
    float s[4]; float sum = 0.f;
#pragma unroll
    for (int e = 0; e < 4; e++) { s[e] = __expf(z[e] - mx); sum += s[e]; }
    const float inv = 1.f / sum;
#pragma unroll
    for (int e = 0; e < 4; e++) s[e] *= inv;
    int e0 = 0; float v0 = s[0];
#pragma unroll
    for (int e = 1; e < 4; e++) if (s[e] > v0) { v0 = s[e]; e0 = e; }
    int e1 = -1; float v1 = -1.f;
#pragma unroll
    for (int e = 0; e < 4; e++) if (e != e0 && s[e] > v1) { v1 = s[e]; e1 = e; }
    const float r = __expf(v1 - v0);
    const float w0 = 1.f / (1.f + r);
    const int m = b * HW_DIM + p0 + tl;
    topw[m * 2] = w0;
    topw[m * 2 + 1] = 1.f - w0;
    atomicOr(&pmask, (1u << e0) | (1u << (4 + e1)));
  }
  __syncthreads();
  if (tid == 0) atomicOr(present, pmask);
  const int nchunk = cnt * 48;
  for (int ci = tid; ci < nchunk; ci += 512) {
    const int row = ci / 48, c8 = ci - row * 48;
    short8 v = *(const short8*)&lxs[row][c8 * 8];
    *(short8*)&xb[(size_t)(b * HW_DIM + p0 + row) * C_DIM + c8 * 8] = v;
  }
}

// -- GEMM1 (r12 proven): 128x128, BK=32, 4 waves, 3 bufs, 1 barrier/step ------
__global__ __launch_bounds__(256, 3) void gemm_1b(
    const ushort_t* __restrict__ A, const ushort_t* __restrict__ Bw,
    const float* __restrict__ bias, const float* __restrict__ topw,
    const unsigned int* __restrict__ presentp, ushort_t* __restrict__ hOut) {
  constexpr int KDIM = C_DIM, BM = 128, BN = 128, BK = 32;
  constexpr int KT = KDIM / BK;                    // 12
  constexpr int NTN = NH / BN;                     // 12
  constexpr int ASZ = BM * BK;                     // 8 KB
  __shared__ ushort_t smem[6 * ASZ];               // 48 KB

  const int nwg = NTN * (NTOK / BM);
  const int orig = blockIdx.x;
  const int xcd = orig & 7;
  const int qq = nwg >> 3, rr = nwg & 7;
  const int wg = (xcd < rr ? xcd * (qq + 1) : rr * (qq + 1) + (xcd - rr) * qq)
               + (orig >> 3);
  const int mt = wg / NTN, nt = wg % NTN;
  const int m0 = mt * BM, n0 = nt * BN;

  const int tid = threadIdx.x;
  const int lane = tid & 63;
  const int wid = tid >> 6;
  const int wm = wid >> 1, wn = wid & 1;           // wave tile 64x64
  const int lanel = lane & 15, laneq = lane >> 4;

  auto stage = [&](int t) {
    const int buf = t % 3;
    ushort_t* dstA = smem + buf * ASZ;
    ushort_t* dstB = smem + 3 * ASZ + buf * ASZ;
    const int kb = t * BK;
#pragma unroll
    for (int li = 0; li < 2; ++li) {
      const int P = (li * 256 + tid) * 16;
      const int row = P >> 6;
      const int cb = (P & 63) ^ (((row >> 1) & 3) << 4);
      gload_lds16(&A[(size_t)(m0 + row) * KDIM + kb + (cb >> 1)],
                  (char*)dstA + P);
    }
#pragma unroll
    for (int li = 0; li < 2; ++li) {
      const int P = (li * 256 + tid) * 16;
      const int row = P >> 6;
      const int cb = (P & 63) ^ (((row >> 1) & 3) << 4);
      gload_lds16(&Bw[(size_t)(n0 + row) * KDIM + kb + (cb >> 1)],
                  (char*)dstB + P);
    }
  };

  f32x4 acc[4][4] = {};
  const int cbr = (laneq * 16) ^ (((lanel >> 1) & 3) << 4);

  stage(0);
  stage(1);
  for (int t = 0; t < KT; ++t) {
    if (t + 1 < KT)
      asm volatile("s_waitcnt vmcnt(4)" ::: "memory");
    else
      asm volatile("s_waitcnt vmcnt(0)" ::: "memory");
    __builtin_amdgcn_sched_barrier(0);
    __builtin_amdgcn_s_barrier();                  // the ONLY barrier per step
    __builtin_amdgcn_sched_barrier(0);
    if (t + 2 < KT) stage(t + 2);
    const int buf = t % 3;
    const char* Ab = (const char*)(smem + buf * ASZ) + (wm * 64 + lanel) * 64;
    const char* Bb =
        (const char*)(smem + 3 * ASZ + buf * ASZ) + (wn * 64 + lanel) * 64;
    short8 av[4], bv[4];
#pragma unroll
    for (int i = 0; i < 4; ++i) av[i] = *(const short8*)(Ab + i * 1024 + cbr);
#pragma unroll
    for (int j = 0; j < 4; ++j) bv[j] = *(const short8*)(Bb + j * 1024 + cbr);
    __builtin_amdgcn_s_setprio(1);
#pragma unroll
    for (int i = 0; i < 4; ++i)
#pragma unroll
      for (int j = 0; j < 4; ++j)
        acc[i][j] = __builtin_amdgcn_mfma_f32_16x16x32_bf16(
            av[i], bv[j], acc[i][j], 0, 0, 0);
    __builtin_amdgcn_s_setprio(0);
  }

  const unsigned int pm = *presentp;
  __syncthreads();
  ushort_t* tr = smem;                             // 128x128 bf16 = 32 KB
  const int e = n0 / HID_DIM;
  const float P0 = (float)((pm >> e) & 1u);
  const float P1 = (float)((pm >> (4 + e)) & 1u);
#pragma unroll
  for (int mi = 0; mi < 4; ++mi) {
    const int r0 = wm * 64 + mi * 16 + laneq * 4;
    const int mg = m0 + r0;
    const float4 t0 = *(const float4*)&topw[mg * 2];
    const float4 t1 = *(const float4*)&topw[mg * 2 + 4];
    const float cj[4] = {P0 * t0.x + P1 * t0.y, P0 * t0.z + P1 * t0.w,
                         P0 * t1.x + P1 * t1.y, P0 * t1.z + P1 * t1.w};
#pragma unroll
    for (int ni = 0; ni < 4; ++ni) {
      const int cl = wn * 64 + ni * 16 + lanel;
      const float bvv = bias[n0 + cl];
#pragma unroll
      for (int j = 0; j < 4; ++j) {
        float v = fmaxf(acc[mi][ni][j] + bvv, 0.f);
        tr[(r0 + j) * 128 + cl] = f2bf(cj[j] * v);
      }
    }
  }
  __syncthreads();
#pragma unroll
  for (int it = 0; it < 8; ++it) {
    const int c = it * 256 + tid;
    const int row = c >> 4, cr = c & 15;
    *(short8*)&hOut[(size_t)(m0 + row) * NH + n0 + cr * 8] =
        *(const short8*)&tr[row * 128 + cr * 8];
  }
}

// -- GEMM2: 128x128, BK=32, 2 waves, A 3-buf LDS + B direct (r19/r20 body) ----
// split=1: grid 1176; half = orig&1 processes K-steps [half*24, half*24+24);
//   half0 -> out (+bias terms), half1 -> raw fp32 partial pout1.
// split=0: grid 588; full K (r20 exact behavior), writes out.
__global__ __launch_bounds__(128, 3) void gemm_bd(
    const ushort_t* __restrict__ A, const ushort_t* __restrict__ Wf,
    const float* __restrict__ bias, const float* __restrict__ topw,
    const unsigned int* __restrict__ presentp, float* __restrict__ outp,
    float* __restrict__ pout1, int split) {
  constexpr int KDIM = NH, BM = 128, BN = 128, BK = 32;
  constexpr int KTFULL = KDIM / BK;                // 48
  constexpr int NTN = C_DIM / BN;                  // 3
  constexpr int ASZ = BM * BK;                     // 8 KB
  __shared__ ushort_t smem[3 * ASZ];               // 24 KB

  const int orig = blockIdx.x;
  const int sub = split ? (orig >> 1) : orig;      // tile id 0..587
  const int half = split ? (orig & 1) : 0;
  const int nsteps = split ? (KTFULL / 2) : KTFULL;
  const int ks0 = half * nsteps;

  const int nwg = NTN * (NTOK / BM);               // 588
  const int xcd = sub & 7;
  const int qq = nwg >> 3, rr = nwg & 7;
  const int wg = (xcd < rr ? xcd * (qq + 1) : rr * (qq + 1) + (xcd - rr) * qq)
               + (sub >> 3);
  const int mt = wg / NTN, nt = wg % NTN;
  const int m0 = mt * BM, n0 = nt * BN;

  const int tid = threadIdx.x;
  const int lane = tid & 63;
  const int wn = tid >> 6;                         // wave col-half (0/1)
  const int lanel = lane & 15, laneq = lane >> 4;

  const ushort_t* wbase =
      Wf + (size_t)nt * KTFULL * 4096 + wn * 2048 + lane * 8;

  auto stage = [&](int t) {                        // A only: 8KB, 4/thread
    ushort_t* dst = smem + (t % 3) * ASZ;
    const int kb = (ks0 + t) * BK;
#pragma unroll
    for (int li = 0; li < 4; ++li) {
      const int P = (li * 128 + tid) * 16;
      const int row = P >> 6;
      const int cb = (P & 63) ^ (((row >> 1) & 3) << 4);
      gload_lds16(&A[(size_t)(m0 + row) * KDIM + kb + (cb >> 1)],
                  (char*)dst + P);
    }
  };
  auto ldB = [&](int t, short8* bv) {              // plain loads -> VGPRs
    const ushort_t* p = wbase + (size_t)(ks0 + t) * 4096;
#pragma unroll
    for (int j = 0; j < 4; ++j) bv[j] = *(const short8*)(p + j * 512);
  };

  f32x4 acc[8][4] = {};
  const int cbr = (laneq * 16) ^ (((lanel >> 1) & 3) << 4);

  short8 bvA[4], bvB[4];

  auto step = [&](int t, short8* cur) {
    if (t + 1 < nsteps)
      asm volatile("s_waitcnt vmcnt(10)" ::: "memory");
    else
      asm volatile("s_waitcnt vmcnt(4)" ::: "memory");
    __builtin_amdgcn_sched_barrier(0);
    __builtin_amdgcn_s_barrier();                  // one barrier per step
    __builtin_amdgcn_sched_barrier(0);
    if (t + 2 < nsteps) stage(t + 2);
    const char* Ab = (const char*)(smem + (t % 3) * ASZ) + lanel * 64;
    short8 av[8];
#pragma unroll
    for (int i = 0; i < 8; ++i) av[i] = *(const short8*)(Ab + i * 1024 + cbr);
    __builtin_amdgcn_s_setprio(1);
#pragma unroll
    for (int i = 0; i < 8; ++i)
#pragma unroll
      for (int j = 0; j < 4; ++j)
        acc[i][j] = __builtin_amdgcn_mfma_f32_16x16x32_bf16(
            av[i], cur[j], acc[i][j], 0, 0, 0);
    __builtin_amdgcn_s_setprio(0);
    if (t + 2 < nsteps) ldB(t + 2, cur);           // refill freed bv set
  };

  stage(0);
  ldB(0, bvA);
  stage(1);
  ldB(1, bvB);
  for (int t = 0; t < nsteps; t += 2) {            // nsteps even (24 / 48)
    step(t, bvA);
    step(t + 1, bvB);
  }

  if (half == 0) {
    // write out WITH bias/coef terms
    const unsigned int pm = *presentp;
    float B0[4], B1[4];
#pragma unroll
    for (int ni = 0; ni < 4; ++ni) {
      const int o = n0 + wn * 64 + ni * 16 + lanel;
      float s0 = 0.f, s1 = 0.f;
#pragma unroll
      for (int e2 = 0; e2 < 4; ++e2) {
        const float bb = bias[e2 * C_DIM + o];
        s0 += (float)((pm >> e2) & 1u) * bb;
        s1 += (float)((pm >> (4 + e2)) & 1u) * bb;
      }
      B0[ni] = s0; B1[ni] = s1;
    }
#pragma unroll
    for (int mi = 0; mi < 8; ++mi) {
      const int mg = m0 + mi * 16 + laneq * 4;
      const float4 t0 = *(const float4*)&topw[mg * 2];
      const float4 t1 = *(const float4*)&topw[mg * 2 + 4];
      const int bb2 = mg / HW_DIM;
      const int p = mg - bb2 * HW_DIM;             // 4 consecutive p, same b
#pragma unroll
      for (int ni = 0; ni < 4; ++ni) {
        const int o = n0 + wn * 64 + ni * 16 + lanel;
        float4 v;
        v.x = acc[mi][ni][0] + t0.x * B0[ni] + t0.y * B1[ni];
        v.y = acc[mi][ni][1] + t0.z * B0[ni] + t0.w * B1[ni];
        v.z = acc[mi][ni][2] + t1.x * B0[ni] + t1.y * B1[ni];
        v.w = acc[mi][ni][3] + t1.z * B0[ni] + t1.w * B1[ni];
        *(float4*)&outp[((size_t)bb2 * C_DIM + o) * HW_DIM + p] = v;
      }
    }
  } else {
    // raw partial to pout1 (same layout as out)
#pragma unroll
    for (int mi = 0; mi < 8; ++mi) {
      const int mg = m0 + mi * 16 + laneq * 4;
      const int bb2 = mg / HW_DIM;
      const int p = mg - bb2 * HW_DIM;
#pragma unroll
      for (int ni = 0; ni < 4; ++ni) {
        const int o = n0 + wn * 64 + ni * 16 + lanel;
        float4 v;
        v.x = acc[mi][ni][0];
        v.y = acc[mi][ni][1];
        v.z = acc[mi][ni][2];
        v.w = acc[mi][ni][3];
        *(float4*)&pout1[((size_t)bb2 * C_DIM + o) * HW_DIM + p] = v;
      }
    }
  }
}

// ---- reduce: out += pout1 (9.63M floats = 2.41M float4) ---------------------
__global__ __launch_bounds__(256) void reduce_kernel(
    float* __restrict__ out, const float* __restrict__ p1) {
  const size_t n4 = (size_t)NTOK * C_DIM / 4;      // 2408448
  const size_t stride = (size_t)gridDim.x * 256;
  for (size_t i = blockIdx.x * 256 + threadIdx.x; i < n4; i += stride) {
    float4 a = ((const float4*)out)[i];
    const float4 b = ((const float4*)p1)[i];
    a.x += b.x; a.y += b.y; a.z += b.z; a.w += b.w;
    ((float4*)out)[i] = a;
  }
}

extern "C" void kernel_launch(void* const* d_in, const int* in_sizes, int n_in,
                              void* d_out, int out_size, void* d_ws, size_t ws_size,
                              hipStream_t stream) {
  const float* x  = (const float*)d_in[0];
  const float* gw = (const float*)d_in[1];
  const float* gb = (const float*)d_in[2];
  const float* w1 = (const float*)d_in[3];
  const float* b1 = (const float*)d_in[4];
  const float* w2 = (const float*)d_in[5];
  const float* b2 = (const float*)d_in[6];
  float* out = (float*)d_out;

  char* ws = (char*)d_ws;
  ushort_t* xb = (ushort_t*)ws;   ws += (size_t)NTOK * C_DIM * 2;   // 19.27MB
  ushort_t* hdnS = (ushort_t*)ws; ws += (size_t)NTOK * NH * 2;      // 77.07MB
  ushort_t* W1b = (ushort_t*)ws;  ws += (size_t)WSZ * 2;            // 1.18MB
  ushort_t* W2f = (ushort_t*)ws;  ws += (size_t)WSZ * 2;            // 1.18MB
  float* topw = (float*)ws;       ws += (size_t)NTOK * 2 * 4;       // 0.20MB
  unsigned int* present = (unsigned int*)ws; ws += 256;
  float* pout1 = (float*)ws;      ws += (size_t)NTOK * C_DIM * 4;   // 38.54MB

  const size_t needed = (size_t)(ws - (char*)d_ws);
  const int split = (ws_size >= needed) ? 1 : 0;

  prep_kernel<<<dim3(WSZ / 256), dim3(256), 0, stream>>>(
      w1, w2, W1b, W2f, present);
  gate_kernel<<<dim3(B_DIM, 13), dim3(512), 0, stream>>>(
      x, gw, gb, xb, topw, present);
  gemm_1b<<<dim3((NTOK / 128) * (NH / 128)), dim3(256), 0, stream>>>(
      xb, W1b, b1, topw, present, hdnS);
  const int g2 = (NTOK / 128) * (C_DIM / 128);     // 588
  gemm_bd<<<dim3(split ? 2 * g2 : g2), dim3(128), 0, stream>>>(
      hdnS, W2f, b2, topw, present, out, pout1, split);
  if (split)
    reduce_kernel<<<dim3(2048), dim3(256), 0, stream>>>(out, pout1);
}

// Round 22
// 140.302 us; speedup vs baseline: 2.3303x; 2.3303x over previous
//
#include <hip/hip_runtime.h>
#include <hip/hip_bf16.h>
#include <stdint.h>

// ConvMoE: B=32, C=384, H=W=28, E=4, HID=384, K=2. N tokens = 25088.
// r22 = r21 with the launch_bounds regression fixed: gemm_bd back to
// (128, 2) — r21's (128, 3) capped VGPRs and spilled acc to scratch
// (VGPR 112->84, FETCH 43->350MB, 53us->231us).
// GEMM1: r12's 128x128/BK=32/4-wave/3-buf kernel (53.1us proven).
// GEMM2: r19/r20's 2-wave direct-B kernel, split-K=2:
//   half0 -> out (+bias/coef terms), half1 -> fp32 partial; reduce adds.
// Runtime ws_size guard: falls back to full-K (r20 exact) if ws too small.
#define B_DIM 32
#define C_DIM 384
#define HW_DIM 784
#define E_DIM 4
#define HID_DIM 384
#define NTOK (B_DIM * HW_DIM)   // 25088
#define NH (E_DIM * HID_DIM)    // 1536
#define WSZ 589824              // NH*C_DIM

using short8 = __attribute__((ext_vector_type(8))) short;
using f32x4  = __attribute__((ext_vector_type(4))) float;
typedef unsigned short ushort_t;

__device__ __forceinline__ ushort_t f2bf(float f) {
  __hip_bfloat16 h = __float2bfloat16(f);
  return __builtin_bit_cast(ushort_t, h);
}

__device__ __forceinline__ void gload_lds16(const void* g, void* l) {
  __builtin_amdgcn_global_load_lds(
      (const __attribute__((address_space(1))) unsigned int*)g,
      (__attribute__((address_space(3))) unsigned int*)l, 16, 0, 0);
}

// ---- kernel 1: W1 linear bf16 + W2 fragment-packed (+ present=0) ------------
__global__ __launch_bounds__(256) void prep_kernel(
    const float* __restrict__ w1, const float* __restrict__ w2,
    ushort_t* __restrict__ W1b, ushort_t* __restrict__ W2f,
    unsigned int* __restrict__ present) {
  int i = blockIdx.x * 256 + threadIdx.x;
  if (i == 0) *present = 0u;
  if (i >= WSZ) return;
  W1b[i] = f2bf(w1[i]);                             // [e*HID+d][c] linear
  {
    // W2f: nt(3) ks(48) chunks of [wn(2)][ni(4)][lane(64)][t(8)]
    int r = i;
    const int nt = r / 196608; r -= nt * 196608;
    const int ks = r / 4096;   r -= ks * 4096;
    const int wn = r >> 11;
    const int ni = (r >> 9) & 3;
    const int ln = (r >> 3) & 63;
    const int tt = r & 7;
    const int o = nt * 128 + wn * 64 + ni * 16 + (ln & 15);
    const int kg = ks * 32 + (ln >> 4) * 8 + tt;
    const int e = kg / HID_DIM, d = kg - e * HID_DIM;
    W2f[i] = f2bf(w2[((size_t)e * C_DIM + o) * HID_DIM + d]);  // w2 [E][C][HID]
  }
}

// ------- kernel 2: gate + softmax + top2 + x -> bf16 [N][C] (512 thr) --------
__global__ __launch_bounds__(512) void gate_kernel(
    const float* __restrict__ x, const float* __restrict__ gw,
    const float* __restrict__ gb, ushort_t* __restrict__ xb,
    float* __restrict__ topw, unsigned int* __restrict__ present) {
  __shared__ __align__(16) ushort_t lxs[64][392];
  __shared__ float pscore[8][64][4];
  __shared__ unsigned int pmask;
  const int b = blockIdx.x;
  const int p0 = blockIdx.y * 64;
  const int cnt = min(64, HW_DIM - p0);
  const int tid = threadIdx.x;
  const int cg = tid >> 6, tl = tid & 63;
  if (tid == 0) pmask = 0u;
  float a0 = 0.f, a1 = 0.f, a2 = 0.f, a3 = 0.f;
  const bool valid = tl < cnt;
  if (valid) {
    const float* xp = x + (size_t)b * C_DIM * HW_DIM + p0 + tl;
    for (int c = cg; c < C_DIM; c += 8) {
      const float v = xp[(size_t)c * HW_DIM];
      lxs[tl][c] = f2bf(v);
      const float4 g = *(const float4*)&gw[c * 4];
      a0 += v * g.x; a1 += v * g.y; a2 += v * g.z; a3 += v * g.w;
    }
  }
  pscore[cg][tl][0] = a0; pscore[cg][tl][1] = a1;
  pscore[cg][tl][2] = a2; pscore[cg][tl][3] = a3;
  __syncthreads();
  if (cg == 0 && valid) {
    float z[4];
#pragma unroll
    for (int e = 0; e < 4; e++) {
      float s = gb[e];
#pragma unroll
      for (int g8 = 0; g8 < 8; g8++) s += pscore[g8][tl][e];
      z[e] = s;
    }
    const float mx = fmaxf(fmaxf(z[0], z[1]), fmaxf(z[2], z[3]));
    float s[4]; float sum = 0.f;
#pragma unroll
    for (int e = 0; e < 4; e++) { s[e] = __expf(z[e] - mx); sum += s[e]; }
    const float inv = 1.f / sum;
#pragma unroll
    for (int e = 0; e < 4; e++) s[e] *= inv;
    int e0 = 0; float v0 = s[0];
#pragma unroll
    for (int e = 1; e < 4; e++) if (s[e] > v0) { v0 = s[e]; e0 = e; }
    int e1 = -1; float v1 = -1.f;
#pragma unroll
    for (int e = 0; e < 4; e++) if (e != e0 && s[e] > v1) { v1 = s[e]; e1 = e; }
    const float r = __expf(v1 - v0);
    const float w0 = 1.f / (1.f + r);
    const int m = b * HW_DIM + p0 + tl;
    topw[m * 2] = w0;
    topw[m * 2 + 1] = 1.f - w0;
    atomicOr(&pmask, (1u << e0) | (1u << (4 + e1)));
  }
  __syncthreads();
  if (tid == 0) atomicOr(present, pmask);
  const int nchunk = cnt * 48;
  for (int ci = tid; ci < nchunk; ci += 512) {
    const int row = ci / 48, c8 = ci - row * 48;
    short8 v = *(const short8*)&lxs[row][c8 * 8];
    *(short8*)&xb[(size_t)(b * HW_DIM + p0 + row) * C_DIM + c8 * 8] = v;
  }
}

// -- GEMM1 (r12 proven): 128x128, BK=32, 4 waves, 3 bufs, 1 barrier/step ------
__global__ __launch_bounds__(256, 3) void gemm_1b(
    const ushort_t* __restrict__ A, const ushort_t* __restrict__ Bw,
    const float* __restrict__ bias, const float* __restrict__ topw,
    const unsigned int* __restrict__ presentp, ushort_t* __restrict__ hOut) {
  constexpr int KDIM = C_DIM, BM = 128, BN = 128, BK = 32;
  constexpr int KT = KDIM / BK;                    // 12
  constexpr int NTN = NH / BN;                     // 12
  constexpr int ASZ = BM * BK;                     // 8 KB
  __shared__ ushort_t smem[6 * ASZ];               // 48 KB

  const int nwg = NTN * (NTOK / BM);
  const int orig = blockIdx.x;
  const int xcd = orig & 7;
  const int qq = nwg >> 3, rr = nwg & 7;
  const int wg = (xcd < rr ? xcd * (qq + 1) : rr * (qq + 1) + (xcd - rr) * qq)
               + (orig >> 3);
  const int mt = wg / NTN, nt = wg % NTN;
  const int m0 = mt * BM, n0 = nt * BN;

  const int tid = threadIdx.x;
  const int lane = tid & 63;
  const int wid = tid >> 6;
  const int wm = wid >> 1, wn = wid & 1;           // wave tile 64x64
  const int lanel = lane & 15, laneq = lane >> 4;

  auto stage = [&](int t) {
    const int buf = t % 3;
    ushort_t* dstA = smem + buf * ASZ;
    ushort_t* dstB = smem + 3 * ASZ + buf * ASZ;
    const int kb = t * BK;
#pragma unroll
    for (int li = 0; li < 2; ++li) {
      const int P = (li * 256 + tid) * 16;
      const int row = P >> 6;
      const int cb = (P & 63) ^ (((row >> 1) & 3) << 4);
      gload_lds16(&A[(size_t)(m0 + row) * KDIM + kb + (cb >> 1)],
                  (char*)dstA + P);
    }
#pragma unroll
    for (int li = 0; li < 2; ++li) {
      const int P = (li * 256 + tid) * 16;
      const int row = P >> 6;
      const int cb = (P & 63) ^ (((row >> 1) & 3) << 4);
      gload_lds16(&Bw[(size_t)(n0 + row) * KDIM + kb + (cb >> 1)],
                  (char*)dstB + P);
    }
  };

  f32x4 acc[4][4] = {};
  const int cbr = (laneq * 16) ^ (((lanel >> 1) & 3) << 4);

  stage(0);
  stage(1);
  for (int t = 0; t < KT; ++t) {
    if (t + 1 < KT)
      asm volatile("s_waitcnt vmcnt(4)" ::: "memory");
    else
      asm volatile("s_waitcnt vmcnt(0)" ::: "memory");
    __builtin_amdgcn_sched_barrier(0);
    __builtin_amdgcn_s_barrier();                  // the ONLY barrier per step
    __builtin_amdgcn_sched_barrier(0);
    if (t + 2 < KT) stage(t + 2);
    const int buf = t % 3;
    const char* Ab = (const char*)(smem + buf * ASZ) + (wm * 64 + lanel) * 64;
    const char* Bb =
        (const char*)(smem + 3 * ASZ + buf * ASZ) + (wn * 64 + lanel) * 64;
    short8 av[4], bv[4];
#pragma unroll
    for (int i = 0; i < 4; ++i) av[i] = *(const short8*)(Ab + i * 1024 + cbr);
#pragma unroll
    for (int j = 0; j < 4; ++j) bv[j] = *(const short8*)(Bb + j * 1024 + cbr);
    __builtin_amdgcn_s_setprio(1);
#pragma unroll
    for (int i = 0; i < 4; ++i)
#pragma unroll
      for (int j = 0; j < 4; ++j)
        acc[i][j] = __builtin_amdgcn_mfma_f32_16x16x32_bf16(
            av[i], bv[j], acc[i][j], 0, 0, 0);
    __builtin_amdgcn_s_setprio(0);
  }

  const unsigned int pm = *presentp;
  __syncthreads();
  ushort_t* tr = smem;                             // 128x128 bf16 = 32 KB
  const int e = n0 / HID_DIM;
  const float P0 = (float)((pm >> e) & 1u);
  const float P1 = (float)((pm >> (4 + e)) & 1u);
#pragma unroll
  for (int mi = 0; mi < 4; ++mi) {
    const int r0 = wm * 64 + mi * 16 + laneq * 4;
    const int mg = m0 + r0;
    const float4 t0 = *(const float4*)&topw[mg * 2];
    const float4 t1 = *(const float4*)&topw[mg * 2 + 4];
    const float cj[4] = {P0 * t0.x + P1 * t0.y, P0 * t0.z + P1 * t0.w,
                         P0 * t1.x + P1 * t1.y, P0 * t1.z + P1 * t1.w};
#pragma unroll
    for (int ni = 0; ni < 4; ++ni) {
      const int cl = wn * 64 + ni * 16 + lanel;
      const float bvv = bias[n0 + cl];
#pragma unroll
      for (int j = 0; j < 4; ++j) {
        float v = fmaxf(acc[mi][ni][j] + bvv, 0.f);
        tr[(r0 + j) * 128 + cl] = f2bf(cj[j] * v);
      }
    }
  }
  __syncthreads();
#pragma unroll
  for (int it = 0; it < 8; ++it) {
    const int c = it * 256 + tid;
    const int row = c >> 4, cr = c & 15;
    *(short8*)&hOut[(size_t)(m0 + row) * NH + n0 + cr * 8] =
        *(const short8*)&tr[row * 128 + cr * 8];
  }
}

// -- GEMM2: 128x128, BK=32, 2 waves, A 3-buf LDS + B direct (r19/r20 body) ----
// split=1: grid 1176; half = orig&1 processes K-steps [half*24, half*24+24);
//   half0 -> out (+bias terms), half1 -> raw fp32 partial pout1.
// split=0: grid 588; full K (r20 exact behavior), writes out.
__global__ __launch_bounds__(128, 2) void gemm_bd(
    const ushort_t* __restrict__ A, const ushort_t* __restrict__ Wf,
    const float* __restrict__ bias, const float* __restrict__ topw,
    const unsigned int* __restrict__ presentp, float* __restrict__ outp,
    float* __restrict__ pout1, int split) {
  constexpr int KDIM = NH, BM = 128, BN = 128, BK = 32;
  constexpr int KTFULL = KDIM / BK;                // 48
  constexpr int NTN = C_DIM / BN;                  // 3
  constexpr int ASZ = BM * BK;                     // 8 KB
  __shared__ ushort_t smem[3 * ASZ];               // 24 KB

  const int orig = blockIdx.x;
  const int sub = split ? (orig >> 1) : orig;      // tile id 0..587
  const int half = split ? (orig & 1) : 0;
  const int nsteps = split ? (KTFULL / 2) : KTFULL;
  const int ks0 = half * nsteps;

  const int nwg = NTN * (NTOK / BM);               // 588
  const int xcd = sub & 7;
  const int qq = nwg >> 3, rr = nwg & 7;
  const int wg = (xcd < rr ? xcd * (qq + 1) : rr * (qq + 1) + (xcd - rr) * qq)
               + (sub >> 3);
  const int mt = wg / NTN, nt = wg % NTN;
  const int m0 = mt * BM, n0 = nt * BN;

  const int tid = threadIdx.x;
  const int lane = tid & 63;
  const int wn = tid >> 6;                         // wave col-half (0/1)
  const int lanel = lane & 15, laneq = lane >> 4;

  const ushort_t* wbase =
      Wf + (size_t)nt * KTFULL * 4096 + wn * 2048 + lane * 8;

  auto stage = [&](int t) {                        // A only: 8KB, 4/thread
    ushort_t* dst = smem + (t % 3) * ASZ;
    const int kb = (ks0 + t) * BK;
#pragma unroll
    for (int li = 0; li < 4; ++li) {
      const int P = (li * 128 + tid) * 16;
      const int row = P >> 6;
      const int cb = (P & 63) ^ (((row >> 1) & 3) << 4);
      gload_lds16(&A[(size_t)(m0 + row) * KDIM + kb + (cb >> 1)],
                  (char*)dst + P);
    }
  };
  auto ldB = [&](int t, short8* bv) {              // plain loads -> VGPRs
    const ushort_t* p = wbase + (size_t)(ks0 + t) * 4096;
#pragma unroll
    for (int j = 0; j < 4; ++j) bv[j] = *(const short8*)(p + j * 512);
  };

  f32x4 acc[8][4] = {};
  const int cbr = (laneq * 16) ^ (((lanel >> 1) & 3) << 4);

  short8 bvA[4], bvB[4];

  auto step = [&](int t, short8* cur) {
    if (t + 1 < nsteps)
      asm volatile("s_waitcnt vmcnt(10)" ::: "memory");
    else
      asm volatile("s_waitcnt vmcnt(4)" ::: "memory");
    __builtin_amdgcn_sched_barrier(0);
    __builtin_amdgcn_s_barrier();                  // one barrier per step
    __builtin_amdgcn_sched_barrier(0);
    if (t + 2 < nsteps) stage(t + 2);
    const char* Ab = (const char*)(smem + (t % 3) * ASZ) + lanel * 64;
    short8 av[8];
#pragma unroll
    for (int i = 0; i < 8; ++i) av[i] = *(const short8*)(Ab + i * 1024 + cbr);
    __builtin_amdgcn_s_setprio(1);
#pragma unroll
    for (int i = 0; i < 8; ++i)
#pragma unroll
      for (int j = 0; j < 4; ++j)
        acc[i][j] = __builtin_amdgcn_mfma_f32_16x16x32_bf16(
            av[i], cur[j], acc[i][j], 0, 0, 0);
    __builtin_amdgcn_s_setprio(0);
    if (t + 2 < nsteps) ldB(t + 2, cur);           // refill freed bv set
  };

  stage(0);
  ldB(0, bvA);
  stage(1);
  ldB(1, bvB);
  for (int t = 0; t < nsteps; t += 2) {            // nsteps even (24 / 48)
    step(t, bvA);
    step(t + 1, bvB);
  }

  if (half == 0) {
    // write out WITH bias/coef terms
    const unsigned int pm = *presentp;
    float B0[4], B1[4];
#pragma unroll
    for (int ni = 0; ni < 4; ++ni) {
      const int o = n0 + wn * 64 + ni * 16 + lanel;
      float s0 = 0.f, s1 = 0.f;
#pragma unroll
      for (int e2 = 0; e2 < 4; ++e2) {
        const float bb = bias[e2 * C_DIM + o];
        s0 += (float)((pm >> e2) & 1u) * bb;
        s1 += (float)((pm >> (4 + e2)) & 1u) * bb;
      }
      B0[ni] = s0; B1[ni] = s1;
    }
#pragma unroll
    for (int mi = 0; mi < 8; ++mi) {
      const int mg = m0 + mi * 16 + laneq * 4;
      const float4 t0 = *(const float4*)&topw[mg * 2];
      const float4 t1 = *(const float4*)&topw[mg * 2 + 4];
      const int bb2 = mg / HW_DIM;
      const int p = mg - bb2 * HW_DIM;             // 4 consecutive p, same b
#pragma unroll
      for (int ni = 0; ni < 4; ++ni) {
        const int o = n0 + wn * 64 + ni * 16 + lanel;
        float4 v;
        v.x = acc[mi][ni][0] + t0.x * B0[ni] + t0.y * B1[ni];
        v.y = acc[mi][ni][1] + t0.z * B0[ni] + t0.w * B1[ni];
        v.z = acc[mi][ni][2] + t1.x * B0[ni] + t1.y * B1[ni];
        v.w = acc[mi][ni][3] + t1.z * B0[ni] + t1.w * B1[ni];
        *(float4*)&outp[((size_t)bb2 * C_DIM + o) * HW_DIM + p] = v;
      }
    }
  } else {
    // raw partial to pout1 (same layout as out)
#pragma unroll
    for (int mi = 0; mi < 8; ++mi) {
      const int mg = m0 + mi * 16 + laneq * 4;
      const int bb2 = mg / HW_DIM;
      const int p = mg - bb2 * HW_DIM;
#pragma unroll
      for (int ni = 0; ni < 4; ++ni) {
        const int o = n0 + wn * 64 + ni * 16 + lanel;
        float4 v;
        v.x = acc[mi][ni][0];
        v.y = acc[mi][ni][1];
        v.z = acc[mi][ni][2];
        v.w = acc[mi][ni][3];
        *(float4*)&pout1[((size_t)bb2 * C_DIM + o) * HW_DIM + p] = v;
      }
    }
  }
}

// ---- reduce: out += pout1 (9.63M floats = 2.41M float4) ---------------------
__global__ __launch_bounds__(256) void reduce_kernel(
    float* __restrict__ out, const float* __restrict__ p1) {
  const size_t n4 = (size_t)NTOK * C_DIM / 4;      // 2408448
  const size_t stride = (size_t)gridDim.x * 256;
  for (size_t i = blockIdx.x * 256 + threadIdx.x; i < n4; i += stride) {
    float4 a = ((const float4*)out)[i];
    const float4 b = ((const float4*)p1)[i];
    a.x += b.x; a.y += b.y; a.z += b.z; a.w += b.w;
    ((float4*)out)[i] = a;
  }
}

extern "C" void kernel_launch(void* const* d_in, const int* in_sizes, int n_in,
                              void* d_out, int out_size, void* d_ws, size_t ws_size,
                              hipStream_t stream) {
  const float* x  = (const float*)d_in[0];
  const float* gw = (const float*)d_in[1];
  const float* gb = (const float*)d_in[2];
  const float* w1 = (const float*)d_in[3];
  const float* b1 = (const float*)d_in[4];
  const float* w2 = (const float*)d_in[5];
  const float* b2 = (const float*)d_in[6];
  float* out = (float*)d_out;

  char* ws = (char*)d_ws;
  ushort_t* xb = (ushort_t*)ws;   ws += (size_t)NTOK * C_DIM * 2;   // 19.27MB
  ushort_t* hdnS = (ushort_t*)ws; ws += (size_t)NTOK * NH * 2;      // 77.07MB
  ushort_t* W1b = (ushort_t*)ws;  ws += (size_t)WSZ * 2;            // 1.18MB
  ushort_t* W2f = (ushort_t*)ws;  ws += (size_t)WSZ * 2;            // 1.18MB
  float* topw = (float*)ws;       ws += (size_t)NTOK * 2 * 4;       // 0.20MB
  unsigned int* present = (unsigned int*)ws; ws += 256;
  float* pout1 = (float*)ws;      ws += (size_t)NTOK * C_DIM * 4;   // 38.54MB

  const size_t needed = (size_t)(ws - (char*)d_ws);
  const int split = (ws_size >= needed) ? 1 : 0;

  prep_kernel<<<dim3(WSZ / 256), dim3(256), 0, stream>>>(
      w1, w2, W1b, W2f, present);
  gate_kernel<<<dim3(B_DIM, 13), dim3(512), 0, stream>>>(
      x, gw, gb, xb, topw, present);
  gemm_1b<<<dim3((NTOK / 128) * (NH / 128)), dim3(256), 0, stream>>>(
      xb, W1b, b1, topw, present, hdnS);
  const int g2 = (NTOK / 128) * (C_DIM / 128);     // 588
  gemm_bd<<<dim3(split ? 2 * g2 : g2), dim3(128), 0, stream>>>(
      hdnS, W2f, b2, topw, present, out, pout1, split);
  if (split)
    reduce_kernel<<<dim3(2048), dim3(256), 0, stream>>>(out, pout1);
}

// Round 23
// 116.643 us; speedup vs baseline: 2.8030x; 1.2028x over previous
//
#include <hip/hip_runtime.h>
#include <hip/hip_bf16.h>
#include <stdint.h>

// ConvMoE: B=32, C=384, H=W=28, E=4, HID=384, K=2. N tokens = 25088.
// FINAL (r20 best, 116.7us): per-kernel best-of composition.
// GEMM1 (K=384): r12's 128x128/BK=32/4-wave/3-buf/single-barrier/counted-
//   vmcnt kernel (53.1us). GEMM2 (K=1536): r19's 2-wave direct-B structure
//   (B pre-packed per-lane fragments, plain loads; A 3-buf LDS) (52.9us).
#define B_DIM 32
#define C_DIM 384
#define HW_DIM 784
#define E_DIM 4
#define HID_DIM 384
#define NTOK (B_DIM * HW_DIM)   // 25088
#define NH (E_DIM * HID_DIM)    // 1536
#define WSZ 589824              // NH*C_DIM

using short8 = __attribute__((ext_vector_type(8))) short;
using f32x4  = __attribute__((ext_vector_type(4))) float;
typedef unsigned short ushort_t;

__device__ __forceinline__ ushort_t f2bf(float f) {
  __hip_bfloat16 h = __float2bfloat16(f);
  return __builtin_bit_cast(ushort_t, h);
}

__device__ __forceinline__ void gload_lds16(const void* g, void* l) {
  __builtin_amdgcn_global_load_lds(
      (const __attribute__((address_space(1))) unsigned int*)g,
      (__attribute__((address_space(3))) unsigned int*)l, 16, 0, 0);
}

// ---- kernel 1: W1 linear bf16 + W2 fragment-packed (+ present=0) ------------
// W2f chunk per (nt,ks): [wn(2)][ni(4)][lane(64)][t(8)] = 4096 elems = 8KB.
// Fragment: o = nt*128 + wn*64 + ni*16 + (lane&15), k = ks*32+(lane>>4)*8+t.
__global__ __launch_bounds__(256) void prep_kernel(
    const float* __restrict__ w1, const float* __restrict__ w2,
    ushort_t* __restrict__ W1b, ushort_t* __restrict__ W2f,
    unsigned int* __restrict__ present) {
  int i = blockIdx.x * 256 + threadIdx.x;
  if (i == 0) *present = 0u;
  if (i >= WSZ) return;
  W1b[i] = f2bf(w1[i]);                             // [e*HID+d][c] linear
  {
    // W2f: nt(3) ks(48)
    int r = i;
    const int nt = r / 196608; r -= nt * 196608;
    const int ks = r / 4096;   r -= ks * 4096;
    const int wn = r >> 11;
    const int ni = (r >> 9) & 3;
    const int ln = (r >> 3) & 63;
    const int tt = r & 7;
    const int o = nt * 128 + wn * 64 + ni * 16 + (ln & 15);
    const int kg = ks * 32 + (ln >> 4) * 8 + tt;
    const int e = kg / HID_DIM, d = kg - e * HID_DIM;
    W2f[i] = f2bf(w2[((size_t)e * C_DIM + o) * HID_DIM + d]);  // w2 [E][C][HID]
  }
}

// ------- kernel 2: gate + softmax + top2 + x -> bf16 [N][C] (512 thr) --------
__global__ __launch_bounds__(512) void gate_kernel(
    const float* __restrict__ x, const float* __restrict__ gw,
    const float* __restrict__ gb, ushort_t* __restrict__ xb,
    float* __restrict__ topw, unsigned int* __restrict__ present) {
  __shared__ __align__(16) ushort_t lxs[64][392];
  __shared__ float pscore[8][64][4];
  __shared__ unsigned int pmask;
  const int b = blockIdx.x;
  const int p0 = blockIdx.y * 64;
  const int cnt = min(64, HW_DIM - p0);
  const int tid = threadIdx.x;
  const int cg = tid >> 6, tl = tid & 63;
  if (tid == 0) pmask = 0u;
  float a0 = 0.f, a1 = 0.f, a2 = 0.f, a3 = 0.f;
  const bool valid = tl < cnt;
  if (valid) {
    const float* xp = x + (size_t)b * C_DIM * HW_DIM + p0 + tl;
    for (int c = cg; c < C_DIM; c += 8) {
      const float v = xp[(size_t)c * HW_DIM];
      lxs[tl][c] = f2bf(v);
      const float4 g = *(const float4*)&gw[c * 4];
      a0 += v * g.x; a1 += v * g.y; a2 += v * g.z; a3 += v * g.w;
    }
  }
  pscore[cg][tl][0] = a0; pscore[cg][tl][1] = a1;
  pscore[cg][tl][2] = a2; pscore[cg][tl][3] = a3;
  __syncthreads();
  if (cg == 0 && valid) {
    float z[4];
#pragma unroll
    for (int e = 0; e < 4; e++) {
      float s = gb[e];
#pragma unroll
      for (int g8 = 0; g8 < 8; g8++) s += pscore[g8][tl][e];
      z[e] = s;
    }
    const float mx = fmaxf(fmaxf(z[0], z[1]), fmaxf(z[2], z[3]));
    float s[4]; float sum = 0.f;
#pragma unroll
    for (int e = 0; e < 4; e++) { s[e] = __expf(z[e] - mx); sum += s[e]; }
    const float inv = 1.f / sum;
#pragma unroll
    for (int e = 0; e < 4; e++) s[e] *= inv;
    int e0 = 0; float v0 = s[0];
#pragma unroll
    for (int e = 1; e < 4; e++) if (s[e] > v0) { v0 = s[e]; e0 = e; }
    int e1 = -1; float v1 = -1.f;
#pragma unroll
    for (int e = 0; e < 4; e++) if (e != e0 && s[e] > v1) { v1 = s[e]; e1 = e; }
    const float r = __expf(v1 - v0);
    const float w0 = 1.f / (1.f + r);
    const int m = b * HW_DIM + p0 + tl;
    topw[m * 2] = w0;
    topw[m * 2 + 1] = 1.f - w0;
    atomicOr(&pmask, (1u << e0) | (1u << (4 + e1)));
  }
  __syncthreads();
  if (tid == 0) atomicOr(present, pmask);
  const int nchunk = cnt * 48;
  for (int ci = tid; ci < nchunk; ci += 512) {
    const int row = ci / 48, c8 = ci - row * 48;
    short8 v = *(const short8*)&lxs[row][c8 * 8];
    *(short8*)&xb[(size_t)(b * HW_DIM + p0 + row) * C_DIM + c8 * 8] = v;
  }
}

// -- GEMM1 (r12 proven): 128x128, BK=32, 4 waves, 3 bufs, 1 barrier/step ------
__global__ __launch_bounds__(256, 3) void gemm_1b(
    const ushort_t* __restrict__ A, const ushort_t* __restrict__ Bw,
    const float* __restrict__ bias, const float* __restrict__ topw,
    const unsigned int* __restrict__ presentp, ushort_t* __restrict__ hOut) {
  constexpr int KDIM = C_DIM, BM = 128, BN = 128, BK = 32;
  constexpr int KT = KDIM / BK;                    // 12
  constexpr int NTN = NH / BN;                     // 12
  constexpr int ASZ = BM * BK;                     // 8 KB
  __shared__ ushort_t smem[6 * ASZ];               // 48 KB

  const int nwg = NTN * (NTOK / BM);
  const int orig = blockIdx.x;
  const int xcd = orig & 7;
  const int qq = nwg >> 3, rr = nwg & 7;
  const int wg = (xcd < rr ? xcd * (qq + 1) : rr * (qq + 1) + (xcd - rr) * qq)
               + (orig >> 3);
  const int mt = wg / NTN, nt = wg % NTN;
  const int m0 = mt * BM, n0 = nt * BN;

  const int tid = threadIdx.x;
  const int lane = tid & 63;
  const int wid = tid >> 6;
  const int wm = wid >> 1, wn = wid & 1;           // wave tile 64x64
  const int lanel = lane & 15, laneq = lane >> 4;

  auto stage = [&](int t) {
    const int buf = t % 3;
    ushort_t* dstA = smem + buf * ASZ;
    ushort_t* dstB = smem + 3 * ASZ + buf * ASZ;
    const int kb = t * BK;
#pragma unroll
    for (int li = 0; li < 2; ++li) {
      const int P = (li * 256 + tid) * 16;
      const int row = P >> 6;
      const int cb = (P & 63) ^ (((row >> 1) & 3) << 4);
      gload_lds16(&A[(size_t)(m0 + row) * KDIM + kb + (cb >> 1)],
                  (char*)dstA + P);
    }
#pragma unroll
    for (int li = 0; li < 2; ++li) {
      const int P = (li * 256 + tid) * 16;
      const int row = P >> 6;
      const int cb = (P & 63) ^ (((row >> 1) & 3) << 4);
      gload_lds16(&Bw[(size_t)(n0 + row) * KDIM + kb + (cb >> 1)],
                  (char*)dstB + P);
    }
  };

  f32x4 acc[4][4] = {};
  const int cbr = (laneq * 16) ^ (((lanel >> 1) & 3) << 4);

  stage(0);
  stage(1);
  for (int t = 0; t < KT; ++t) {
    if (t + 1 < KT)
      asm volatile("s_waitcnt vmcnt(4)" ::: "memory");
    else
      asm volatile("s_waitcnt vmcnt(0)" ::: "memory");
    __builtin_amdgcn_sched_barrier(0);
    __builtin_amdgcn_s_barrier();                  // the ONLY barrier per step
    __builtin_amdgcn_sched_barrier(0);
    if (t + 2 < KT) stage(t + 2);
    const int buf = t % 3;
    const char* Ab = (const char*)(smem + buf * ASZ) + (wm * 64 + lanel) * 64;
    const char* Bb =
        (const char*)(smem + 3 * ASZ + buf * ASZ) + (wn * 64 + lanel) * 64;
    short8 av[4], bv[4];
#pragma unroll
    for (int i = 0; i < 4; ++i) av[i] = *(const short8*)(Ab + i * 1024 + cbr);
#pragma unroll
    for (int j = 0; j < 4; ++j) bv[j] = *(const short8*)(Bb + j * 1024 + cbr);
    __builtin_amdgcn_s_setprio(1);
#pragma unroll
    for (int i = 0; i < 4; ++i)
#pragma unroll
      for (int j = 0; j < 4; ++j)
        acc[i][j] = __builtin_amdgcn_mfma_f32_16x16x32_bf16(
            av[i], bv[j], acc[i][j], 0, 0, 0);
    __builtin_amdgcn_s_setprio(0);
  }

  const unsigned int pm = *presentp;
  __syncthreads();
  ushort_t* tr = smem;                             // 128x128 bf16 = 32 KB
  const int e = n0 / HID_DIM;
  const float P0 = (float)((pm >> e) & 1u);
  const float P1 = (float)((pm >> (4 + e)) & 1u);
#pragma unroll
  for (int mi = 0; mi < 4; ++mi) {
    const int r0 = wm * 64 + mi * 16 + laneq * 4;
    const int mg = m0 + r0;
    const float4 t0 = *(const float4*)&topw[mg * 2];
    const float4 t1 = *(const float4*)&topw[mg * 2 + 4];
    const float cj[4] = {P0 * t0.x + P1 * t0.y, P0 * t0.z + P1 * t0.w,
                         P0 * t1.x + P1 * t1.y, P0 * t1.z + P1 * t1.w};
#pragma unroll
    for (int ni = 0; ni < 4; ++ni) {
      const int cl = wn * 64 + ni * 16 + lanel;
      const float bvv = bias[n0 + cl];
#pragma unroll
      for (int j = 0; j < 4; ++j) {
        float v = fmaxf(acc[mi][ni][j] + bvv, 0.f);
        tr[(r0 + j) * 128 + cl] = f2bf(cj[j] * v);
      }
    }
  }
  __syncthreads();
#pragma unroll
  for (int it = 0; it < 8; ++it) {
    const int c = it * 256 + tid;
    const int row = c >> 4, cr = c & 15;
    *(short8*)&hOut[(size_t)(m0 + row) * NH + n0 + cr * 8] =
        *(const short8*)&tr[row * 128 + cr * 8];
  }
}

// -- GEMM2 (r19 proven): 128x128, BK=32, 2 waves, A 3-buf LDS + B direct ------
// Per step t: [vmcnt(10); barrier; stage A(t+2); ds_read av; MFMA; ldB(t+2)].
__global__ __launch_bounds__(128, 2) void gemm_bd(
    const ushort_t* __restrict__ A, const ushort_t* __restrict__ Wf,
    const float* __restrict__ bias, const float* __restrict__ topw,
    const unsigned int* __restrict__ presentp, float* __restrict__ outp) {
  constexpr int KDIM = NH, BM = 128, BN = 128, BK = 32;
  constexpr int KT = KDIM / BK;                    // 48
  constexpr int NTN = C_DIM / BN;                  // 3
  constexpr int ASZ = BM * BK;                     // 8 KB
  __shared__ ushort_t smem[3 * ASZ];               // 24 KB

  const int nwg = NTN * (NTOK / BM);
  const int orig = blockIdx.x;
  const int xcd = orig & 7;
  const int qq = nwg >> 3, rr = nwg & 7;
  const int wg = (xcd < rr ? xcd * (qq + 1) : rr * (qq + 1) + (xcd - rr) * qq)
               + (orig >> 3);
  const int mt = wg / NTN, nt = wg % NTN;
  const int m0 = mt * BM, n0 = nt * BN;

  const int tid = threadIdx.x;
  const int lane = tid & 63;
  const int wn = tid >> 6;                         // wave col-half (0/1)
  const int lanel = lane & 15, laneq = lane >> 4;

  const ushort_t* wbase = Wf + (size_t)nt * KT * 4096 + wn * 2048 + lane * 8;

  auto stage = [&](int t) {                        // A only: 8KB, 4/thread
    ushort_t* dst = smem + (t % 3) * ASZ;
    const int kb = t * BK;
#pragma unroll
    for (int li = 0; li < 4; ++li) {
      const int P = (li * 128 + tid) * 16;
      const int row = P >> 6;
      const int cb = (P & 63) ^ (((row >> 1) & 3) << 4);
      gload_lds16(&A[(size_t)(m0 + row) * KDIM + kb + (cb >> 1)],
                  (char*)dst + P);
    }
  };
  auto ldB = [&](int t, short8* bv) {              // plain loads -> VGPRs
    const ushort_t* p = wbase + (size_t)t * 4096;
#pragma unroll
    for (int j = 0; j < 4; ++j) bv[j] = *(const short8*)(p + j * 512);
  };

  f32x4 acc[8][4] = {};
  const int cbr = (laneq * 16) ^ (((lanel >> 1) & 3) << 4);

  short8 bvA[4], bvB[4];

  auto step = [&](int t, short8* cur) {
    if (t + 1 < KT)
      asm volatile("s_waitcnt vmcnt(10)" ::: "memory");
    else
      asm volatile("s_waitcnt vmcnt(4)" ::: "memory");
    __builtin_amdgcn_sched_barrier(0);
    __builtin_amdgcn_s_barrier();                  // one barrier per step
    __builtin_amdgcn_sched_barrier(0);
    if (t + 2 < KT) stage(t + 2);
    const char* Ab = (const char*)(smem + (t % 3) * ASZ) + lanel * 64;
    short8 av[8];
#pragma unroll
    for (int i = 0; i < 8; ++i) av[i] = *(const short8*)(Ab + i * 1024 + cbr);
    __builtin_amdgcn_s_setprio(1);
#pragma unroll
    for (int i = 0; i < 8; ++i)
#pragma unroll
      for (int j = 0; j < 4; ++j)
        acc[i][j] = __builtin_amdgcn_mfma_f32_16x16x32_bf16(
            av[i], cur[j], acc[i][j], 0, 0, 0);
    __builtin_amdgcn_s_setprio(0);
    if (t + 2 < KT) ldB(t + 2, cur);               // refill freed bv set
  };

  stage(0);
  ldB(0, bvA);
  stage(1);
  ldB(1, bvB);
  for (int t = 0; t < KT; t += 2) {                // KT = 48
    step(t, bvA);
    step(t + 1, bvB);
  }

  const unsigned int pm = *presentp;
  float B0[4], B1[4];
#pragma unroll
  for (int ni = 0; ni < 4; ++ni) {
    const int o = n0 + wn * 64 + ni * 16 + lanel;
    float s0 = 0.f, s1 = 0.f;
#pragma unroll
    for (int e2 = 0; e2 < 4; ++e2) {
      const float bb = bias[e2 * C_DIM + o];
      s0 += (float)((pm >> e2) & 1u) * bb;
      s1 += (float)((pm >> (4 + e2)) & 1u) * bb;
    }
    B0[ni] = s0; B1[ni] = s1;
  }
#pragma unroll
  for (int mi = 0; mi < 8; ++mi) {
    const int mg = m0 + mi * 16 + laneq * 4;
    const float4 t0 = *(const float4*)&topw[mg * 2];
    const float4 t1 = *(const float4*)&topw[mg * 2 + 4];
    const int bb2 = mg / HW_DIM;
    const int p = mg - bb2 * HW_DIM;               // 4 consecutive p, same b
#pragma unroll
    for (int ni = 0; ni < 4; ++ni) {
      const int o = n0 + wn * 64 + ni * 16 + lanel;
      float4 v;
      v.x = acc[mi][ni][0] + t0.x * B0[ni] + t0.y * B1[ni];
      v.y = acc[mi][ni][1] + t0.z * B0[ni] + t0.w * B1[ni];
      v.z = acc[mi][ni][2] + t1.x * B0[ni] + t1.y * B1[ni];
      v.w = acc[mi][ni][3] + t1.z * B0[ni] + t1.w * B1[ni];
      *(float4*)&outp[((size_t)bb2 * C_DIM + o) * HW_DIM + p] = v;
    }
  }
}

extern "C" void kernel_launch(void* const* d_in, const int* in_sizes, int n_in,
                              void* d_out, int out_size, void* d_ws, size_t ws_size,
                              hipStream_t stream) {
  const float* x  = (const float*)d_in[0];
  const float* gw = (const float*)d_in[1];
  const float* gb = (const float*)d_in[2];
  const float* w1 = (const float*)d_in[3];
  const float* b1 = (const float*)d_in[4];
  const float* w2 = (const float*)d_in[5];
  const float* b2 = (const float*)d_in[6];
  float* out = (float*)d_out;

  char* ws = (char*)d_ws;
  ushort_t* xb = (ushort_t*)ws;   ws += (size_t)NTOK * C_DIM * 2;
  ushort_t* hdnS = (ushort_t*)ws; ws += (size_t)NTOK * NH * 2;
  ushort_t* W1b = (ushort_t*)ws;  ws += (size_t)WSZ * 2;
  ushort_t* W2f = (ushort_t*)ws;  ws += (size_t)WSZ * 2;
  float* topw = (float*)ws;       ws += (size_t)NTOK * 2 * 4;
  unsigned int* present = (unsigned int*)ws;

  prep_kernel<<<dim3(WSZ / 256), dim3(256), 0, stream>>>(
      w1, w2, W1b, W2f, present);
  gate_kernel<<<dim3(B_DIM, 13), dim3(512), 0, stream>>>(
      x, gw, gb, xb, topw, present);
  gemm_1b<<<dim3((NTOK / 128) * (NH / 128)), dim3(256), 0, stream>>>(
      xb, W1b, b1, topw, present, hdnS);
  gemm_bd<<<dim3((NTOK / 128) * (C_DIM / 128)), dim3(128), 0, stream>>>(
      hdnS, W2f, b2, topw, present, out);
}